// Round 6
// baseline (3129.062 us; speedup 1.0000x reference)
//
#include <hip/hip_runtime.h>
#include <hip/hip_bf16.h>
#include <stdint.h>

// GRU-D encoder, MI355X persistent-kernel implementation, round 6.
// B=256, S=200, D=64, H=512, TD=8.
// Per 16-row chain (rb): 4 barrier-free gate WGs (32 cols/wave; Ur+Uh
// register-resident = 256 VGPR; direct per-wave A-frag loads), 2 z-producer
// WGs (Uz resident; z computed in parallel with the r->Uh chain), 2 x-part
// producers, 1 gamma producer. 9 WGs/rb x 16 rb = 144 WGs.
// All spins fuel-bounded (fail fast, no hang).

typedef unsigned short u16;
typedef unsigned int   u32;
typedef unsigned long long u64;
typedef short bfrag  __attribute__((ext_vector_type(8)));
typedef u16   u16x8  __attribute__((ext_vector_type(8)));
typedef float f32x4  __attribute__((ext_vector_type(4)));

#define NB 256
#define NS 200
#define ND 64
#define NH 512

#define MFMA(a,b,c) __builtin_amdgcn_mfma_f32_16x16x32_bf16((a),(b),(c),0,0,0)

union UQ  { u16x8 h; bfrag s; u64 u[2]; uint4 q; };

__device__ __forceinline__ float b2f(u16 v){ union { float f; u32 u; } c; c.u = ((u32)v) << 16; return c.f; }
__device__ __forceinline__ u16 f2b(float f){ union { float f; u32 u; } c; c.f = f; u32 r = c.u + 0x7FFFu + ((c.u >> 16) & 1u); return (u16)(r >> 16); }
__device__ __forceinline__ float sigm(float x){ return 1.f / (1.f + __expf(-x)); }
__device__ __forceinline__ float tanh_f(float x){ return 1.f - 2.f / (1.f + __expf(2.f * x)); }

// agent-scope (coherence-point) ops: cross-XCD visible without L2 inv/wb fences
__device__ __forceinline__ u64 cload64(const void* p){
  return __hip_atomic_load((const u64*)p, __ATOMIC_RELAXED, __HIP_MEMORY_SCOPE_AGENT);
}
__device__ __forceinline__ void cstore64(void* p, u64 v){
  __hip_atomic_store((u64*)p, v, __ATOMIC_RELAXED, __HIP_MEMORY_SCOPE_AGENT);
}
__device__ __forceinline__ u32 cload32(const u32* p){
  return __hip_atomic_load(p, __ATOMIC_RELAXED, __HIP_MEMORY_SCOPE_AGENT);
}
__device__ __forceinline__ void cstore32(u32* p, u32 v){
  __hip_atomic_store(p, v, __ATOMIC_RELAXED, __HIP_MEMORY_SCOPE_AGENT);
}
// Wave-uniform vector poll: lane polls base[widx]; exits when ALL lanes'
// words reach tgt. Fuel-bounded (uniform exit) -> fail fast, no GPU hang.
__device__ __forceinline__ bool spin_vec(const u32* base, int widx, u32 tgt){
  const u32* p = base + widx;
  int fuel = 1 << 21;
  while (true) {
    u32 v = cload32(p);
    if (__all(v >= tgt)) return true;
    __builtin_amdgcn_s_sleep(2);
    if (--fuel == 0) return false;
  }
}
// load 8 consecutive f32 of a weight row, round to bf16 MFMA fragment
__device__ __forceinline__ bfrag ldfrag(const float* src){
  f32x4 lo = *(const f32x4*)src;
  f32x4 hi = *(const f32x4*)(src + 4);
  UQ z;
  z.h[0]=f2b(lo[0]); z.h[1]=f2b(lo[1]); z.h[2]=f2b(lo[2]); z.h[3]=f2b(lo[3]);
  z.h[4]=f2b(hi[0]); z.h[5]=f2b(hi[1]); z.h[6]=f2b(hi[2]); z.h[7]=f2b(hi[3]);
  return z.s;
}

// ---------------- setup kernels ----------------

__global__ void transpose_k(const float* __restrict__ Wout, float* __restrict__ WT){
  int i = blockIdx.x * 256 + threadIdx.x;
  if (i < 520 * 512) { int k = i >> 9, ho = i & 511; WT[i] = Wout[ho * 520 + k]; }
}

__global__ void mean1_k(const float* __restrict__ x, const float* __restrict__ mask,
                        float* __restrict__ PX, float* __restrict__ PM){
  int s = blockIdx.x, tid = threadIdx.x;
  __shared__ float lx[256], lm[256];
  float xa = 0.f, ma = 0.f;
  for (int i = tid; i < NB * ND; i += 256) {
    int b = i >> 6, d = i & 63;
    size_t ix = ((size_t)b * NS + s) * 64 + d;
    float m = mask[ix];
    xa += m * x[ix]; ma += m;
  }
  lx[tid] = xa; lm[tid] = ma;
  __syncthreads();
  if (tid < 64) {
    PX[(size_t)s * 64 + tid] = lx[tid] + lx[tid + 64] + lx[tid + 128] + lx[tid + 192];
    PM[(size_t)s * 64 + tid] = lm[tid] + lm[tid + 64] + lm[tid + 128] + lm[tid + 192];
  }
}

__global__ void mean2_k(const float* __restrict__ PX, const float* __restrict__ PM,
                        float* __restrict__ XMEAN){
  int d = threadIdx.x;
  float sx = 0.f, sm = 0.f;
  for (int s = 0; s < NS; ++s){ sx += PX[s * 64 + d]; sm += PM[s * 64 + d]; }
  XMEAN[d] = sx / fmaxf(sm, 1.f);
}

// per-(b,d) time chains: delta scan, x_last scan, x_hat; writes [s][b][d] bf16
__global__ void prep_k(const float* __restrict__ x, const float* __restrict__ mask,
                       const float* __restrict__ tc, const float* __restrict__ wdgx,
                       const float* __restrict__ bdgx, const float* __restrict__ XMEAN,
                       u16* __restrict__ XHAT, u16* __restrict__ MASKB, u16* __restrict__ DELTA){
  int g = blockIdx.x * 256 + threadIdx.x;
  int b = g >> 6, d = g & 63;
  float xmean = XMEAN[d], wx = wdgx[d], bx = bdgx[d];
  float xl = 0.f, del = 0.f, tprev = 0.f, mprev = 1.f;
  for (int s = 0; s < NS; ++s){
    float tv = tc[b * NS + s];
    float dtv = (s == 0) ? 0.f : (tv - tprev);
    tprev = tv;
    del = dtv + (1.f - mprev) * del;
    size_t ix = ((size_t)b * NS + s) * 64 + d;
    float m = mask[ix], xv = x[ix];
    float gx = __expf(-fmaxf(0.f, wx * del + bx));
    float xh = m * xv + (1.f - m) * (gx * xl + (1.f - gx) * xmean);
    size_t ox = ((size_t)s * NB + b) * 64 + d;
    XHAT[ox] = f2b(xh); MASKB[ox] = f2b(m); DELTA[ox] = f2b(del);
    xl = m * xv + (1.f - m) * xl;
    mprev = m;
  }
}

// ---------------- persistent recurrent kernel ----------------
// grid = 144 WGs (16 rb x 9), 256 threads (4 waves).
// role 0..3 : gate WG (32 cols/wave of r and Uh; barrier-free)
// role 4..5 : z producer (z = sigm(xz + Uz h_dec), 64 cols/wave)
// role 6..7 : x-part producer (cols p*768..+768 of [z|r|h] pre-activations)
// role 8    : gamma producer
// Flags per rb (stride 64 u32): FH[16] @0, FR[16] @16, FZ[2] @32, FX[2] @34, FG @36.
__global__ __launch_bounds__(256, 1) void grud_rnn(
    const float* __restrict__ Um, const float* __restrict__ Wm, const float* __restrict__ Vm,
    const float* __restrict__ bv, const float* __restrict__ Wdg, const float* __restrict__ bdg,
    const u16* __restrict__ XHAT, const u16* __restrict__ MASKB, const u16* __restrict__ DELTA,
    u16* __restrict__ HDECB, u16* __restrict__ RHB, u16* __restrict__ XPART,
    u16* __restrict__ GAMB, u16* __restrict__ ZZB, u16* __restrict__ HALL,
    u32* __restrict__ flags)
{
  const int tid = threadIdx.x, lane = tid & 63, wid = tid >> 6, bid = blockIdx.x;
  const int rb = bid / 9, role = bid % 9, m0 = rb * 16;
  const int l16 = lane & 15, krow = lane >> 4;
  const int r4 = lane >> 2, cb = (lane & 3) * 8;
  u32* FB = flags + rb * 64;

  __shared__ u16 panel[64 * 16 * 8];    // producer staging (16 KB)
  __shared__ float xb[4][16 * 34];      // per-wave transpose scratch
  __shared__ int s_ab;
  float* xw = xb[wid];
  const f32x4 Z4 = {0.f, 0.f, 0.f, 0.f};
  if (tid == 0) s_ab = 0;
  __syncthreads();

  if (role < 4) {
    // ================= gate WG (barrier-free, per-wave autonomous) =======
    const int pw = role * 4 + wid;          // publisher index 0..15
    const int cw = role * 128 + wid * 32;   // wave's 32-col strip base
    bfrag BUr[16][2], BUh[16][2];           // 64 frags = 256 VGPR, resident
    #pragma unroll
    for (int kk = 0; kk < 16; ++kk) {
      const size_t ko = (size_t)(kk * 32 + krow * 8);
      #pragma unroll
      for (int t2 = 0; t2 < 2; ++t2) {
        BUr[kk][t2] = ldfrag(Um + (size_t)(512  + cw + t2 * 16 + l16) * 512 + ko);
        BUh[kk][t2] = ldfrag(Um + (size_t)(1024 + cw + t2 * 16 + l16) * 512 + ko);
      }
    }

    for (int t = 0; t < NS; ++t) {
      const int slot = t & 1;
      // early loads: xpart r/h strips + gamma(t+1) (producers run ahead)
      if (!spin_vec(FB + 34, lane & 1, (u32)(t + 1))) return;
      const u16* xpb = XPART + (((size_t)slot * 16 + rb) * 16 + r4) * 1536 + cw + cb;
      u64 xr0 = cload64(xpb + 512),  xr1 = cload64(xpb + 516);
      u64 xh0 = cload64(xpb + 1024), xh1 = cload64(xpb + 1028);
      u64 gm0 = 0, gm1 = 0;
      if (t + 1 < NS) {
        if (!spin_vec(FB + 36, 0, (u32)(t + 1))) return;
        const u16* gpb = GAMB + (((size_t)((t + 1) & 1) * 16 + rb) * 16 + r4) * 512 + cw + cb;
        gm0 = cload64(gpb); gm1 = cload64(gpb + 4);
      }
      // ---- hop 1: h_dec(t) -> per-wave direct A-frag loads ----
      UQ HA[16]; u64 hd0 = 0, hd1 = 0;
      if (t > 0) {
        if (!spin_vec(FB + 0, lane & 15, (u32)t)) return;
        hd0 = cload64(HDECB + (size_t)(m0 + r4) * 512 + cw + cb);
        hd1 = cload64(HDECB + (size_t)(m0 + r4) * 512 + cw + cb + 4);
        #pragma unroll
        for (int kk = 0; kk < 16; ++kk) {
          const u16* p = HDECB + (size_t)(m0 + l16) * 512 + kk * 32 + krow * 8;
          HA[kk].u[0] = cload64(p); HA[kk].u[1] = cload64(p + 4);
        }
      } else {
        #pragma unroll
        for (int kk = 0; kk < 16; ++kk) { HA[kk].u[0] = 0; HA[kk].u[1] = 0; }
      }
      // ---- r GEMM (32 MFMA, 2 indep chains) ----
      f32x4 a0 = Z4, a1 = Z4;
      #pragma unroll
      for (int kk = 0; kk < 16; ++kk) {
        a0 = MFMA(HA[kk].s, BUr[kk][0], a0);
        a1 = MFMA(HA[kk].s, BUr[kk][1], a1);
      }
      #pragma unroll
      for (int j = 0; j < 4; ++j) {
        xw[(krow * 4 + j) * 34 + l16] = a0[j];
        xw[(krow * 4 + j) * 34 + 16 + l16] = a1[j];
      }
      UQ xr_; xr_.u[0] = xr0; xr_.u[1] = xr1;
      UQ hd_; hd_.u[0] = hd0; hd_.u[1] = hd1;
      UQ rh_;
      #pragma unroll
      for (int q = 0; q < 8; ++q) {
        float rv = sigm(b2f(xr_.h[q]) + xw[r4 * 34 + cb + q]);
        rh_.h[q] = f2b(rv * b2f(hd_.h[q]));
      }
      u16* rdst = RHB + (size_t)(m0 + r4) * 512 + cw + cb;
      cstore64(rdst, rh_.u[0]); cstore64(rdst + 4, rh_.u[1]);
      asm volatile("s_waitcnt vmcnt(0)" ::: "memory");
      if (lane == 0) cstore32(FB + 16 + pw, (u32)(t + 1));
      // ---- hop 2: rh all-gather -> Uh GEMM ----
      if (!spin_vec(FB + 16, lane & 15, (u32)(t + 1))) return;
      UQ RA[16];
      #pragma unroll
      for (int kk = 0; kk < 16; ++kk) {
        const u16* p = RHB + (size_t)(m0 + l16) * 512 + kk * 32 + krow * 8;
        RA[kk].u[0] = cload64(p); RA[kk].u[1] = cload64(p + 4);
      }
      if (!spin_vec(FB + 32, lane & 1, (u32)(t + 1))) return;   // z ready
      u64 zz0 = cload64(ZZB + (size_t)(m0 + r4) * 512 + cw + cb);
      u64 zz1 = cload64(ZZB + (size_t)(m0 + r4) * 512 + cw + cb + 4);
      f32x4 h0_ = Z4, h1_ = Z4;
      #pragma unroll
      for (int kk = 0; kk < 16; ++kk) {
        h0_ = MFMA(RA[kk].s, BUh[kk][0], h0_);
        h1_ = MFMA(RA[kk].s, BUh[kk][1], h1_);
      }
      #pragma unroll
      for (int j = 0; j < 4; ++j) {
        xw[(krow * 4 + j) * 34 + l16] = h0_[j];
        xw[(krow * 4 + j) * 34 + 16 + l16] = h1_[j];
      }
      UQ xh_; xh_.u[0] = xh0; xh_.u[1] = xh1;
      UQ zz_; zz_.u[0] = zz0; zz_.u[1] = zz1;
      UQ gm_; gm_.u[0] = gm0; gm_.u[1] = gm1;
      UQ hw_, hdn_;
      #pragma unroll
      for (int q = 0; q < 8; ++q) {
        float til = tanh_f(b2f(xh_.h[q]) + xw[r4 * 34 + cb + q]);
        float z = b2f(zz_.h[q]);
        float hn = (1.f - z) * b2f(hd_.h[q]) + z * til;
        hw_.h[q] = f2b(hn);
        hdn_.h[q] = f2b(b2f(gm_.h[q]) * hn);
      }
      if (t + 1 < NS) {
        u16* hdst = HDECB + (size_t)(m0 + r4) * 512 + cw + cb;
        cstore64(hdst, hdn_.u[0]); cstore64(hdst + 4, hdn_.u[1]);
      }
      asm volatile("s_waitcnt vmcnt(0)" ::: "memory");
      if (lane == 0) cstore32(FB + 0 + pw, (u32)(t + 1));
      // HALL store off the critical path (read only by attn_k later)
      u16* hp = HALL + ((size_t)t * NB + m0 + r4) * 512 + cw + cb;
      *(u64*)hp = hw_.u[0]; *(u64*)(hp + 4) = hw_.u[1];
    }
  } else if (role < 6) {
    // ================= z producer: z = sigm(xz + Uz h_dec) ==============
    const int zi = role - 4;
    const int zc = zi * 256 + wid * 64;     // wave's 64 z-cols
    bfrag BZ[16][4];                        // 64 frags = 256 VGPR, resident
    #pragma unroll
    for (int kk = 0; kk < 16; ++kk)
      #pragma unroll
      for (int ct = 0; ct < 4; ++ct)
        BZ[kk][ct] = ldfrag(Um + (size_t)(zc + ct * 16 + l16) * 512 + kk * 32 + krow * 8);

    for (int t = 0; t < NS; ++t) {
      bool ok = spin_vec(FB + 34, lane & 1, (u32)(t + 1));      // xpart(t)
      if (t > 0) ok = ok && spin_vec(FB + 0, lane & 15, (u32)t); // h_dec(t)
      if (!ok) s_ab = 1;
      __syncthreads();
      if (s_ab) break;
      if (t > 0) {   // stage h_dec [16][512] -> A-frag panel (coalesced)
        const int srow = tid >> 4, sc = (tid & 15) * 32;
        const u16* hs = HDECB + (size_t)(m0 + srow) * 512 + sc;
        u64 a0 = cload64(hs),      a1 = cload64(hs + 4),  a2 = cload64(hs + 8),  a3 = cload64(hs + 12);
        u64 a4 = cload64(hs + 16), a5 = cload64(hs + 20), a6 = cload64(hs + 24), a7 = cload64(hs + 28);
        u16* dp = &panel[((sc >> 3) * 16 + srow) * 8];
        *(u64*)(dp)       = a0; *(u64*)(dp + 4)   = a1;
        *(u64*)(dp + 128) = a2; *(u64*)(dp + 132) = a3;
        *(u64*)(dp + 256) = a4; *(u64*)(dp + 260) = a5;
        *(u64*)(dp + 384) = a6; *(u64*)(dp + 388) = a7;
      }
      __syncthreads();
      u64 xzv[4];
      #pragma unroll
      for (int ct = 0; ct < 4; ++ct)
        xzv[ct] = cload64(XPART + (((size_t)(t & 1) * 16 + rb) * 16 + r4) * 1536
                          + zc + ct * 16 + (lane & 3) * 4);
      f32x4 acc[4] = {Z4, Z4, Z4, Z4};
      if (t > 0) {
        #pragma unroll
        for (int kk = 0; kk < 16; ++kk) {
          bfrag a = *(const bfrag*)&panel[((kk * 4 + krow) * 16 + l16) * 8];
          #pragma unroll
          for (int ct = 0; ct < 4; ++ct) acc[ct] = MFMA(a, BZ[kk][ct], acc[ct]);
        }
      }
      #pragma unroll
      for (int ct = 0; ct < 4; ++ct) {
        #pragma unroll
        for (int j = 0; j < 4; ++j) xw[(krow * 4 + j) * 34 + l16] = acc[ct][j];
        UQ xzq; xzq.u[0] = xzv[ct];
        UQ zq;
        #pragma unroll
        for (int q = 0; q < 4; ++q)
          zq.h[q] = f2b(sigm(b2f(xzq.h[q]) + xw[r4 * 34 + (lane & 3) * 4 + q]));
        cstore64(ZZB + (size_t)(m0 + r4) * 512 + zc + ct * 16 + (lane & 3) * 4, zq.u[0]);
      }
      asm volatile("s_waitcnt vmcnt(0)" ::: "memory");
      __syncthreads();
      if (tid == 0) cstore32(FB + 32 + zi, (u32)(t + 1));
    }
  } else if (role < 8) {
    // ================= x-part producer =================
    const int p = role - 6;
    const int wbase = p * 768 + wid * 192;   // wave col base in [0,1536)
    bfrag BW[12][2], BV2[12][2];
    #pragma unroll
    for (int ct = 0; ct < 12; ++ct)
      #pragma unroll
      for (int kx = 0; kx < 2; ++kx) {
        BW[ct][kx]  = ldfrag(Wm + (size_t)(wbase + ct * 16 + l16) * 64 + kx * 32 + krow * 8);
        BV2[ct][kx] = ldfrag(Vm + (size_t)(wbase + ct * 16 + l16) * 64 + kx * 32 + krow * 8);
      }
    float bias6[6][8];
    #pragma unroll
    for (int grp = 0; grp < 6; ++grp)
      #pragma unroll
      for (int q = 0; q < 8; ++q) bias6[grp][q] = bv[wbase + grp * 32 + cb + q];

    for (int t = 0; t < NS; ++t) {
      bool ok = (t < 2) || spin_vec(FB + 0, lane & 15, (u32)(t - 1));
      if (!ok) s_ab = 1;
      { const int kb = tid >> 4, row = tid & 15;
        const u16* sp = (kb < 8 ? XHAT : MASKB) + ((size_t)t * NB + m0 + row) * 64 + (kb & 7) * 8;
        *(uint4*)&panel[(kb * 16 + row) * 8] = *(const uint4*)sp; }
      __syncthreads();
      if (s_ab) break;
      u16* orow_ = XPART + (((size_t)(t & 1) * 16 + rb) * 16 + r4) * 1536 + wbase;
      #pragma unroll
      for (int grp = 0; grp < 6; ++grp) {
        f32x4 ac0 = Z4, ac1 = Z4;
        #pragma unroll
        for (int kx = 0; kx < 2; ++kx) {
          bfrag ax = *(const bfrag*)&panel[((kx * 4 + krow) * 16 + l16) * 8];
          ac0 = MFMA(ax, BW[grp*2][kx], ac0); ac1 = MFMA(ax, BW[grp*2+1][kx], ac1);
          bfrag am = *(const bfrag*)&panel[((8 + kx * 4 + krow) * 16 + l16) * 8];
          ac0 = MFMA(am, BV2[grp*2][kx], ac0); ac1 = MFMA(am, BV2[grp*2+1][kx], ac1);
        }
        #pragma unroll
        for (int j = 0; j < 4; ++j) { xw[(krow*4+j)*34 + l16] = ac0[j]; xw[(krow*4+j)*34 + 16 + l16] = ac1[j]; }
        UQ ov;
        #pragma unroll
        for (int q = 0; q < 8; ++q) ov.h[q] = f2b(xw[r4 * 34 + cb + q] + bias6[grp][q]);
        cstore64(orow_ + grp * 32 + cb, ov.u[0]); cstore64(orow_ + grp * 32 + cb + 4, ov.u[1]);
      }
      asm volatile("s_waitcnt vmcnt(0)" ::: "memory");
      __syncthreads();
      if (tid == 0) cstore32(FB + 34 + p, (u32)(t + 1));
    }
  } else {
    // ================= gamma producer =================
    bfrag BG[8][2];
    #pragma unroll
    for (int ct = 0; ct < 8; ++ct)
      #pragma unroll
      for (int kx = 0; kx < 2; ++kx)
        BG[ct][kx] = ldfrag(Wdg + (size_t)(wid * 128 + ct * 16 + l16) * 64 + kx * 32 + krow * 8);
    float gb4[4][8];
    #pragma unroll
    for (int grp = 0; grp < 4; ++grp)
      #pragma unroll
      for (int q = 0; q < 8; ++q) gb4[grp][q] = bdg[wid * 128 + grp * 32 + cb + q];

    for (int tt = 1; tt < NS; ++tt) {
      bool ok = (tt < 3) || spin_vec(FB + 0, lane & 15, (u32)(tt - 2));
      if (!ok) s_ab = 1;
      if (tid < 128) {
        const int kb = tid >> 4, row = tid & 15;
        const u16* sp = DELTA + ((size_t)tt * NB + m0 + row) * 64 + kb * 8;
        *(uint4*)&panel[(kb * 16 + row) * 8] = *(const uint4*)sp;
      }
      __syncthreads();
      if (s_ab) break;
      u16* orow_ = GAMB + (((size_t)(tt & 1) * 16 + rb) * 16 + r4) * 512 + wid * 128;
      #pragma unroll
      for (int grp = 0; grp < 4; ++grp) {
        f32x4 ac0 = Z4, ac1 = Z4;
        #pragma unroll
        for (int kx = 0; kx < 2; ++kx) {
          bfrag a = *(const bfrag*)&panel[((kx * 4 + krow) * 16 + l16) * 8];
          ac0 = MFMA(a, BG[grp*2][kx], ac0); ac1 = MFMA(a, BG[grp*2+1][kx], ac1);
        }
        #pragma unroll
        for (int j = 0; j < 4; ++j) { xw[(krow*4+j)*34 + l16] = ac0[j]; xw[(krow*4+j)*34 + 16 + l16] = ac1[j]; }
        UQ ov;
        #pragma unroll
        for (int q = 0; q < 8; ++q)
          ov.h[q] = f2b(__expf(-fmaxf(0.f, xw[r4 * 34 + cb + q] + gb4[grp][q])));
        cstore64(orow_ + grp * 32 + cb, ov.u[0]); cstore64(orow_ + grp * 32 + cb + 4, ov.u[1]);
      }
      asm volatile("s_waitcnt vmcnt(0)" ::: "memory");
      __syncthreads();
      if (tid == 0) cstore32(FB + 36, (u32)tt);
    }
  }
}

// ---------------- post kernels ----------------

__global__ void attn_k(const u16* __restrict__ HALL, const float* __restrict__ av,
                       float* __restrict__ ATTN){
  const int b = blockIdx.x, tid = threadIdx.x, lane = tid & 63, wid = tid >> 6;
  __shared__ float avs[512], wgt[256], red[8];
  for (int i = tid; i < 512; i += 256) avs[i] = av[i];
  __syncthreads();
  float val = -3.0e38f;
  if (tid < NS) {
    const u16* hp = HALL + ((size_t)tid * NB + b) * 512;
    float acc = 0.f;
    for (int h = 0; h < 512; h += 8) {
      UQ w; w.q = *(const uint4*)(hp + h);
      #pragma unroll
      for (int j = 0; j < 8; ++j) acc += b2f(w.h[j]) * avs[h + j];
    }
    val = acc * 0.04419417382415922f;   // 1/sqrt(512)
  }
  float m = val;
  #pragma unroll
  for (int off = 32; off; off >>= 1) m = fmaxf(m, __shfl_xor(m, off, 64));
  if (lane == 0) red[wid] = m;
  __syncthreads();
  m = fmaxf(fmaxf(red[0], red[1]), fmaxf(red[2], red[3]));
  float e = (tid < NS) ? __expf(val - m) : 0.f;
  float sum = e;
  #pragma unroll
  for (int off = 32; off; off >>= 1) sum += __shfl_xor(sum, off, 64);
  if (lane == 0) red[4 + wid] = sum;
  __syncthreads();
  const float ssum = red[4] + red[5] + red[6] + red[7];
  wgt[tid] = e / ssum;
  __syncthreads();
  float a0 = 0.f, a1 = 0.f;
  const int h0 = tid * 2;
  for (int s = 0; s < NS; ++s) {
    float w = wgt[s];
    u32 pr = *(const u32*)(HALL + ((size_t)s * NB + b) * 512 + h0);
    a0 += w * b2f((u16)(pr & 0xFFFFu));
    a1 += w * b2f((u16)(pr >> 16));
  }
  ATTN[(size_t)b * 512 + h0] = a0;
  ATTN[(size_t)b * 512 + h0 + 1] = a1;
}

// 4 batch rows per WG: WT re-read traffic 256MB -> 64MB
__global__ void out_k(const float* __restrict__ ATTN, const float* __restrict__ Ain,
                      const float* __restrict__ WT, const float* __restrict__ bout,
                      float* __restrict__ OUT){
  const int g = blockIdx.x, tid = threadIdx.x;
  __shared__ float ah[4][520];
  for (int i = tid; i < 4 * 520; i += 256) {
    int bb = i / 520, k = i % 520;
    int b = g * 4 + bb;
    ah[bb][k] = (k < 512) ? ATTN[(size_t)b * 512 + k] : Ain[b * 8 + (k - 512)];
  }
  __syncthreads();
  #pragma unroll
  for (int part = 0; part < 2; ++part) {
    const int ho = part * 256 + tid;
    float a0 = bout[ho], a1 = a0, a2 = a0, a3 = a0;
    for (int k = 0; k < 520; ++k) {
      float w = WT[(size_t)k * 512 + ho];
      a0 += ah[0][k] * w; a1 += ah[1][k] * w; a2 += ah[2][k] * w; a3 += ah[3][k] * w;
    }
    OUT[(size_t)(g * 4 + 0) * 512 + ho] = a0;
    OUT[(size_t)(g * 4 + 1) * 512 + ho] = a1;
    OUT[(size_t)(g * 4 + 2) * 512 + ho] = a2;
    OUT[(size_t)(g * 4 + 3) * 512 + ho] = a3;
  }
}

// ---------------- host ----------------

extern "C" void kernel_launch(void* const* d_in, const int* in_sizes, int n_in,
                              void* d_out, int out_size, void* d_ws, size_t ws_size,
                              hipStream_t stream) {
  (void)in_sizes; (void)n_in; (void)out_size; (void)ws_size;
  const float* x    = (const float*)d_in[0];
  const float* a_in = (const float*)d_in[1];
  const float* tc   = (const float*)d_in[2];
  const float* mask = (const float*)d_in[3];
  const float* wdgx = (const float*)d_in[4];
  const float* bdgx = (const float*)d_in[5];
  const float* Wdgh = (const float*)d_in[6];
  const float* bdgh = (const float*)d_in[7];
  const float* Wm   = (const float*)d_in[8];
  const float* Um   = (const float*)d_in[9];
  const float* Vm   = (const float*)d_in[10];
  const float* bvv  = (const float*)d_in[11];
  const float* attv = (const float*)d_in[12];
  const float* Wout = (const float*)d_in[13];
  const float* bout = (const float*)d_in[14];

  char* ws = (char*)d_ws;
  size_t o = 0;
  auto al = [&](size_t sz) { size_t r = o; o += (sz + 255) & ~(size_t)255; return r; };
  u32*   flags = (u32*)  (ws + al(16 * 64 * 4));
  float* XMEAN = (float*)(ws + al(256));
  float* PX    = (float*)(ws + al((size_t)NS * 64 * 4));
  float* PM    = (float*)(ws + al((size_t)NS * 64 * 4));
  u16*   XHAT  = (u16*)  (ws + al((size_t)NS * NB * 64 * 2));
  u16*   MASKB = (u16*)  (ws + al((size_t)NS * NB * 64 * 2));
  u16*   DELTA = (u16*)  (ws + al((size_t)NS * NB * 64 * 2));
  u16*   HDECB = (u16*)  (ws + al((size_t)NB * NH * 2));
  u16*   RHB   = (u16*)  (ws + al((size_t)NB * NH * 2));
  u16*   XPART = (u16*)  (ws + al((size_t)2 * 16 * 16 * 1536 * 2));
  u16*   GAMB  = (u16*)  (ws + al((size_t)2 * 16 * 16 * 512 * 2));
  u16*   ZZB   = (u16*)  (ws + al((size_t)NB * NH * 2));
  u16*   HALL  = (u16*)  (ws + al((size_t)NS * NB * NH * 2));
  float* ATTN  = (float*)(ws + al((size_t)NB * NH * 4));
  float* WT    = (float*)(ws + al((size_t)520 * 512 * 4));

  hipMemsetAsync(flags, 0, 16 * 64 * 4, stream);

  transpose_k<<<(520 * 512 + 255) / 256, 256, 0, stream>>>(Wout, WT);
  mean1_k<<<NS, 256, 0, stream>>>(x, mask, PX, PM);
  mean2_k<<<1, 64, 0, stream>>>(PX, PM, XMEAN);
  prep_k<<<NB * ND / 256, 256, 0, stream>>>(x, mask, tc, wdgx, bdgx, XMEAN, XHAT, MASKB, DELTA);
  grud_rnn<<<144, 256, 0, stream>>>(Um, Wm, Vm, bvv, Wdgh, bdgh, XHAT, MASKB, DELTA,
                                    HDECB, RHB, XPART, GAMB, ZZB, HALL, flags);
  attn_k<<<NB, 256, 0, stream>>>(HALL, attv, ATTN);
  out_k<<<64, 256, 0, stream>>>(ATTN, a_in, WT, bout, (float*)d_out);
}

// Round 7
// 2025.938 us; speedup vs baseline: 1.5445x; 1.5445x over previous
//
#include <hip/hip_runtime.h>
#include <hip/hip_bf16.h>
#include <stdint.h>

// GRU-D encoder, MI355X persistent-kernel implementation, round 7.
// B=256, S=200, D=64, H=512, TD=8.
// Per 16-row chain (rb): 4 gate WGs (r + h-candidate, K=640 fused GEMMs,
// 80 resident B-frags), 4 z-WGs (K=640, 40 frags, same shape as gate hop1),
// 1 gamma producer. Cooperative coalesced LDS staging; store-flags with
// lane-parallel merged polls; 9 WGs/rb x 16 rb = 144 WGs.
// All polls fuel-bounded (fail fast, no GPU hang).

typedef unsigned short u16;
typedef unsigned int   u32;
typedef unsigned long long u64;
typedef short bfrag  __attribute__((ext_vector_type(8)));
typedef u16   u16x8  __attribute__((ext_vector_type(8)));
typedef float f32x4  __attribute__((ext_vector_type(4)));

#define NB 256
#define NS 200
#define ND 64
#define NH 512

#define MFMA(a,b,c) __builtin_amdgcn_mfma_f32_16x16x32_bf16((a),(b),(c),0,0,0)

union UQ { u16x8 h; bfrag s; u64 u[2]; uint4 q; };

__device__ __forceinline__ float b2f(u16 v){ union { float f; u32 u; } c; c.u = ((u32)v) << 16; return c.f; }
__device__ __forceinline__ u16 f2b(float f){ union { float f; u32 u; } c; c.f = f; u32 r = c.u + 0x7FFFu + ((c.u >> 16) & 1u); return (u16)(r >> 16); }
__device__ __forceinline__ float sigm(float x){ return 1.f / (1.f + __expf(-x)); }
__device__ __forceinline__ float tanh_f(float x){ return 1.f - 2.f / (1.f + __expf(2.f * x)); }

// agent-scope (coherence-point) ops
__device__ __forceinline__ u64 cload64(const void* p){
  return __hip_atomic_load((const u64*)p, __ATOMIC_RELAXED, __HIP_MEMORY_SCOPE_AGENT);
}
__device__ __forceinline__ void cstore64(void* p, u64 v){
  __hip_atomic_store((u64*)p, v, __ATOMIC_RELAXED, __HIP_MEMORY_SCOPE_AGENT);
}
__device__ __forceinline__ u32 cload32(const u32* p){
  return __hip_atomic_load(p, __ATOMIC_RELAXED, __HIP_MEMORY_SCOPE_AGENT);
}
__device__ __forceinline__ void cstore32(u32* p, u32 v){
  __hip_atomic_store(p, v, __ATOMIC_RELAXED, __HIP_MEMORY_SCOPE_AGENT);
}
// lane-parallel poll: lane supplies its own word pointer and target; exits
// when ALL lanes satisfied. Fuel-bounded (uniform exit) -> fail fast.
__device__ __forceinline__ bool poll_ge(const u32* wp, u32 tgt){
  int fuel = 1 << 20;
  while (true) {
    u32 v = cload32(wp);
    if (__all(v >= tgt)) return true;
    if (--fuel == 0) return false;
  }
}
// load 8 consecutive f32 of a weight row, round to bf16 MFMA fragment
__device__ __forceinline__ bfrag ldfrag(const float* src){
  f32x4 lo = *(const f32x4*)src;
  f32x4 hi = *(const f32x4*)(src + 4);
  UQ z;
  z.h[0]=f2b(lo[0]); z.h[1]=f2b(lo[1]); z.h[2]=f2b(lo[2]); z.h[3]=f2b(lo[3]);
  z.h[4]=f2b(hi[0]); z.h[5]=f2b(hi[1]); z.h[6]=f2b(hi[2]); z.h[7]=f2b(hi[3]);
  return z.s;
}
// B-frag source for the K=640 concat [U | W | V] (A = [h | x_hat | m])
__device__ __forceinline__ const float* wsrc(const float* Um, const float* Wm,
                                             const float* Vm, int c, int k0){
  if (k0 < 512) return Um + (size_t)c * 512 + k0;
  if (k0 < 576) return Wm + (size_t)c * 64 + (k0 - 512);
  return Vm + (size_t)c * 64 + (k0 - 576);
}

// ---------------- setup kernels ----------------

__global__ void transpose_k(const float* __restrict__ Wout, float* __restrict__ WT){
  int i = blockIdx.x * 256 + threadIdx.x;
  if (i < 520 * 512) { int k = i >> 9, ho = i & 511; WT[i] = Wout[ho * 520 + k]; }
}

__global__ void mean1_k(const float* __restrict__ x, const float* __restrict__ mask,
                        float* __restrict__ PX, float* __restrict__ PM){
  int s = blockIdx.x, tid = threadIdx.x;
  __shared__ float lx[256], lm[256];
  float xa = 0.f, ma = 0.f;
  for (int i = tid; i < NB * ND; i += 256) {
    int b = i >> 6, d = i & 63;
    size_t ix = ((size_t)b * NS + s) * 64 + d;
    float m = mask[ix];
    xa += m * x[ix]; ma += m;
  }
  lx[tid] = xa; lm[tid] = ma;
  __syncthreads();
  if (tid < 64) {
    PX[(size_t)s * 64 + tid] = lx[tid] + lx[tid + 64] + lx[tid + 128] + lx[tid + 192];
    PM[(size_t)s * 64 + tid] = lm[tid] + lm[tid + 64] + lm[tid + 128] + lm[tid + 192];
  }
}

__global__ void mean2_k(const float* __restrict__ PX, const float* __restrict__ PM,
                        float* __restrict__ XMEAN){
  int d = threadIdx.x;
  float sx = 0.f, sm = 0.f;
  for (int s = 0; s < NS; ++s){ sx += PX[s * 64 + d]; sm += PM[s * 64 + d]; }
  XMEAN[d] = sx / fmaxf(sm, 1.f);
}

__global__ void prep_k(const float* __restrict__ x, const float* __restrict__ mask,
                       const float* __restrict__ tc, const float* __restrict__ wdgx,
                       const float* __restrict__ bdgx, const float* __restrict__ XMEAN,
                       u16* __restrict__ XHAT, u16* __restrict__ MASKB, u16* __restrict__ DELTA){
  int g = blockIdx.x * 256 + threadIdx.x;
  int b = g >> 6, d = g & 63;
  float xmean = XMEAN[d], wx = wdgx[d], bx = bdgx[d];
  float xl = 0.f, del = 0.f, tprev = 0.f, mprev = 1.f;
  for (int s = 0; s < NS; ++s){
    float tv = tc[b * NS + s];
    float dtv = (s == 0) ? 0.f : (tv - tprev);
    tprev = tv;
    del = dtv + (1.f - mprev) * del;
    size_t ix = ((size_t)b * NS + s) * 64 + d;
    float m = mask[ix], xv = x[ix];
    float gx = __expf(-fmaxf(0.f, wx * del + bx));
    float xh = m * xv + (1.f - m) * (gx * xl + (1.f - gx) * xmean);
    size_t ox = ((size_t)s * NB + b) * 64 + d;
    XHAT[ox] = f2b(xh); MASKB[ox] = f2b(m); DELTA[ox] = f2b(del);
    xl = m * xv + (1.f - m) * xl;
    mprev = m;
  }
}

// ---------------- persistent recurrent kernel ----------------
// grid = 144 WGs (16 rb x 9), 256 threads (4 waves).
// role 0..3 : gate WG — 32 cols/wave of r AND h-candidate (K=640 fused)
// role 4..7 : z WG    — 32 cols/wave of z (K=640 fused)
// role 8    : gamma producer (double-buffered, paced)
// Flags per rb (stride 64 u32): FH[16]@0, FR[16]@16, FZ[16]@32, FG@48.
__global__ __launch_bounds__(256, 1) void grud_rnn(
    const float* __restrict__ Um, const float* __restrict__ Wm, const float* __restrict__ Vm,
    const float* __restrict__ bv, const float* __restrict__ Wdg, const float* __restrict__ bdg,
    const u16* __restrict__ XHAT, const u16* __restrict__ MASKB, const u16* __restrict__ DELTA,
    u16* __restrict__ HDECB, u16* __restrict__ RHB, u16* __restrict__ ZZB,
    u16* __restrict__ GAMB, u16* __restrict__ HALL, u32* __restrict__ flags)
{
  const int tid = threadIdx.x, lane = tid & 63, wid = tid >> 6, bid = blockIdx.x;
  const int rb = bid / 9, role = bid % 9, m0 = rb * 16;
  const int l16 = lane & 15, krow = lane >> 4;
  const int r4 = lane >> 2, cb = (lane & 3) * 8;
  u32* FB = flags + rb * 64;

  __shared__ u16 panel[80 * 16 * 8];    // A-panel [kbx][row][8] bf16, K=640 (20 KB)
  __shared__ float xb[4][16 * 34];      // per-wave transpose scratch
  __shared__ int s_ab;
  float* xw = xb[wid];
  const f32x4 Z4 = {0.f, 0.f, 0.f, 0.f};
  if (tid == 0) s_ab = 0;
  __syncthreads();

  if (role < 4) {
    // ================= gate WG =================
    const int pw = role * 4 + wid;          // publisher index 0..15
    const int cw = role * 128 + wid * 32;   // wave's 32-col strip
    bfrag BR[20][2], BH[20][2];             // 80 frags = 320 VGPR, resident
    #pragma unroll
    for (int kk = 0; kk < 20; ++kk) {
      const int k0 = kk * 32 + krow * 8;
      #pragma unroll
      for (int t2 = 0; t2 < 2; ++t2) {
        BR[kk][t2] = ldfrag(wsrc(Um, Wm, Vm, 512  + cw + t2 * 16 + l16, k0));
        BH[kk][t2] = ldfrag(wsrc(Um, Wm, Vm, 1024 + cw + t2 * 16 + l16, k0));
      }
    }
    const float br0 = bv[512 + cw + l16],  br1 = bv[512 + cw + 16 + l16];
    const float bh0 = bv[1024 + cw + l16], bh1 = bv[1024 + cw + 16 + l16];

    for (int t = 0; t < NS; ++t) {
      // stage x_hat/mask (kbx 64..79) — static, plain cached loads
      { const int kbx = tid >> 4, row = tid & 15;
        const u16* sp = (kbx < 8 ? XHAT : MASKB) + ((size_t)t * NB + m0 + row) * 64 + (kbx & 7) * 8;
        *(uint4*)&panel[((64 + kbx) * 16 + row) * 8] = *(const uint4*)sp; }
      // merged poll: FH (lanes 0-15) + FG (lane 16)
      if (wid == 0) {
        const u32* wp; u32 tgt;
        if (lane < 16)      { wp = FB + lane; tgt = (u32)t; }
        else if (lane == 16){ wp = FB + 48; tgt = (u32)((t + 1 < NS) ? (t + 1) : (NS - 1)); }
        else                { wp = FB; tgt = 0u; }
        if (!poll_ge(wp, tgt)) s_ab = 1;
      }
      __syncthreads();                       // B1
      if (s_ab) break;
      u64 gm0 = 0, gm1 = 0;
      if (t + 1 < NS) {
        const u16* gpb = GAMB + (((size_t)((t + 1) & 1) * 16 + rb) * 16 + r4) * 512 + cw + cb;
        gm0 = cload64(gpb); gm1 = cload64(gpb + 4);
      }
      // stage h_dec(t) -> panel kbx 0..63 (coalesced agent loads)
      { const int row = tid >> 4, sc = (tid & 15) * 32;
        u16* dp = &panel[((sc >> 3) * 16 + row) * 8];
        if (t > 0) {
          const u16* hs = HDECB + (size_t)(m0 + row) * 512 + sc;
          u64 a0 = cload64(hs),      a1 = cload64(hs + 4),  a2 = cload64(hs + 8),  a3 = cload64(hs + 12);
          u64 a4 = cload64(hs + 16), a5 = cload64(hs + 20), a6 = cload64(hs + 24), a7 = cload64(hs + 28);
          *(u64*)(dp)       = a0; *(u64*)(dp + 4)   = a1;
          *(u64*)(dp + 128) = a2; *(u64*)(dp + 132) = a3;
          *(u64*)(dp + 256) = a4; *(u64*)(dp + 260) = a5;
          *(u64*)(dp + 384) = a6; *(u64*)(dp + 388) = a7;
        } else {
          *(u64*)(dp)       = 0; *(u64*)(dp + 4)   = 0;
          *(u64*)(dp + 128) = 0; *(u64*)(dp + 132) = 0;
          *(u64*)(dp + 256) = 0; *(u64*)(dp + 260) = 0;
          *(u64*)(dp + 384) = 0; *(u64*)(dp + 388) = 0;
        }
      }
      __syncthreads();                       // B2
      // r GEMM: K=640 over [h | x_hat | m]
      f32x4 a0 = {br0, br0, br0, br0}, a1 = {br1, br1, br1, br1};
      #pragma unroll
      for (int kk = 0; kk < 20; ++kk) {
        bfrag a = *(const bfrag*)&panel[((kk * 4 + krow) * 16 + l16) * 8];
        a0 = MFMA(a, BR[kk][0], a0); a1 = MFMA(a, BR[kk][1], a1);
      }
      #pragma unroll
      for (int j = 0; j < 4; ++j) {
        xw[(krow * 4 + j) * 34 + l16] = a0[j];
        xw[(krow * 4 + j) * 34 + 16 + l16] = a1[j];
      }
      UQ hd_; hd_.h = *(const u16x8*)&panel[(((cw + cb) >> 3) * 16 + r4) * 8];
      UQ rh_;
      #pragma unroll
      for (int q = 0; q < 8; ++q) {
        float rv = sigm(xw[r4 * 34 + cb + q]);
        rh_.h[q] = f2b(rv * b2f(hd_.h[q]));
      }
      u16* rdst = RHB + (size_t)(m0 + r4) * 512 + cw + cb;
      cstore64(rdst, rh_.u[0]); cstore64(rdst + 4, rh_.u[1]);
      asm volatile("s_waitcnt vmcnt(0)" ::: "memory");
      if (lane == 0) cstore32(FB + 16 + pw, (u32)(t + 1));
      // merged poll: FR (lanes 0-15) + FZ (lanes 16-31)
      if (wid == 0) {
        const u32* wp; u32 tgt;
        if (lane < 16)      { wp = FB + 16 + lane; tgt = (u32)(t + 1); }
        else if (lane < 32) { wp = FB + 32 + (lane - 16); tgt = (u32)(t + 1); }
        else                { wp = FB; tgt = 0u; }
        if (!poll_ge(wp, tgt)) s_ab = 1;
      }
      __syncthreads();                       // B3 (also: all r-MFMA reads done)
      if (s_ab) break;
      // stage rh -> panel kbx 0..63
      { const int row = tid >> 4, sc = (tid & 15) * 32;
        const u16* rs = RHB + (size_t)(m0 + row) * 512 + sc;
        u64 a0_ = cload64(rs),      a1_ = cload64(rs + 4),  a2_ = cload64(rs + 8),  a3_ = cload64(rs + 12);
        u64 a4_ = cload64(rs + 16), a5_ = cload64(rs + 20), a6_ = cload64(rs + 24), a7_ = cload64(rs + 28);
        u16* dp = &panel[((sc >> 3) * 16 + row) * 8];
        *(u64*)(dp)       = a0_; *(u64*)(dp + 4)   = a1_;
        *(u64*)(dp + 128) = a2_; *(u64*)(dp + 132) = a3_;
        *(u64*)(dp + 256) = a4_; *(u64*)(dp + 260) = a5_;
        *(u64*)(dp + 384) = a6_; *(u64*)(dp + 388) = a7_;
      }
      __syncthreads();                       // B4
      // z for own cols (published by z-WGs; FZ polled at B3)
      u64 zz0 = cload64(ZZB + (size_t)(m0 + r4) * 512 + cw + cb);
      u64 zz1 = cload64(ZZB + (size_t)(m0 + r4) * 512 + cw + cb + 4);
      // h-candidate GEMM: K=640 over [rh | x_hat | m]
      f32x4 h0_ = {bh0, bh0, bh0, bh0}, h1_ = {bh1, bh1, bh1, bh1};
      #pragma unroll
      for (int kk = 0; kk < 20; ++kk) {
        bfrag a = *(const bfrag*)&panel[((kk * 4 + krow) * 16 + l16) * 8];
        h0_ = MFMA(a, BH[kk][0], h0_); h1_ = MFMA(a, BH[kk][1], h1_);
      }
      #pragma unroll
      for (int j = 0; j < 4; ++j) {
        xw[(krow * 4 + j) * 34 + l16] = h0_[j];
        xw[(krow * 4 + j) * 34 + 16 + l16] = h1_[j];
      }
      UQ zz_; zz_.u[0] = zz0; zz_.u[1] = zz1;
      UQ gm_; gm_.u[0] = gm0; gm_.u[1] = gm1;
      UQ hw_, hdn_;
      #pragma unroll
      for (int q = 0; q < 8; ++q) {
        float til = tanh_f(xw[r4 * 34 + cb + q]);
        float z = b2f(zz_.h[q]);
        float hn = (1.f - z) * b2f(hd_.h[q]) + z * til;
        hw_.h[q] = f2b(hn);
        hdn_.h[q] = f2b(b2f(gm_.h[q]) * hn);
      }
      if (t + 1 < NS) {
        u16* hdst = HDECB + (size_t)(m0 + r4) * 512 + cw + cb;
        cstore64(hdst, hdn_.u[0]); cstore64(hdst + 4, hdn_.u[1]);
      }
      asm volatile("s_waitcnt vmcnt(0)" ::: "memory");
      if (lane == 0) cstore32(FB + 0 + pw, (u32)(t + 1));
      // HALL store off the critical path
      u16* hp = HALL + ((size_t)t * NB + m0 + r4) * 512 + cw + cb;
      *(u64*)hp = hw_.u[0]; *(u64*)(hp + 4) = hw_.u[1];
      __syncthreads();                       // B5 (protect panel for next iter)
    }
  } else if (role < 8) {
    // ================= z WG (same shape as gate hop 1) =================
    const int pw = (role - 4) * 4 + wid;
    const int cw = (role - 4) * 128 + wid * 32;
    bfrag BZ[20][2];                        // 40 frags, resident
    #pragma unroll
    for (int kk = 0; kk < 20; ++kk) {
      const int k0 = kk * 32 + krow * 8;
      #pragma unroll
      for (int t2 = 0; t2 < 2; ++t2)
        BZ[kk][t2] = ldfrag(wsrc(Um, Wm, Vm, cw + t2 * 16 + l16, k0));
    }
    const float bz0 = bv[cw + l16], bz1 = bv[cw + 16 + l16];

    for (int t = 0; t < NS; ++t) {
      { const int kbx = tid >> 4, row = tid & 15;
        const u16* sp = (kbx < 8 ? XHAT : MASKB) + ((size_t)t * NB + m0 + row) * 64 + (kbx & 7) * 8;
        *(uint4*)&panel[((64 + kbx) * 16 + row) * 8] = *(const uint4*)sp; }
      if (wid == 0) {
        const u32* wp = (lane < 16) ? (FB + lane) : FB;
        u32 tgt = (lane < 16) ? (u32)t : 0u;
        if (!poll_ge(wp, tgt)) s_ab = 1;
      }
      __syncthreads();                       // B1
      if (s_ab) break;
      { const int row = tid >> 4, sc = (tid & 15) * 32;
        u16* dp = &panel[((sc >> 3) * 16 + row) * 8];
        if (t > 0) {
          const u16* hs = HDECB + (size_t)(m0 + row) * 512 + sc;
          u64 a0 = cload64(hs),      a1 = cload64(hs + 4),  a2 = cload64(hs + 8),  a3 = cload64(hs + 12);
          u64 a4 = cload64(hs + 16), a5 = cload64(hs + 20), a6 = cload64(hs + 24), a7 = cload64(hs + 28);
          *(u64*)(dp)       = a0; *(u64*)(dp + 4)   = a1;
          *(u64*)(dp + 128) = a2; *(u64*)(dp + 132) = a3;
          *(u64*)(dp + 256) = a4; *(u64*)(dp + 260) = a5;
          *(u64*)(dp + 384) = a6; *(u64*)(dp + 388) = a7;
        } else {
          *(u64*)(dp)       = 0; *(u64*)(dp + 4)   = 0;
          *(u64*)(dp + 128) = 0; *(u64*)(dp + 132) = 0;
          *(u64*)(dp + 256) = 0; *(u64*)(dp + 260) = 0;
          *(u64*)(dp + 384) = 0; *(u64*)(dp + 388) = 0;
        }
      }
      __syncthreads();                       // B2
      f32x4 a0 = {bz0, bz0, bz0, bz0}, a1 = {bz1, bz1, bz1, bz1};
      #pragma unroll
      for (int kk = 0; kk < 20; ++kk) {
        bfrag a = *(const bfrag*)&panel[((kk * 4 + krow) * 16 + l16) * 8];
        a0 = MFMA(a, BZ[kk][0], a0); a1 = MFMA(a, BZ[kk][1], a1);
      }
      #pragma unroll
      for (int j = 0; j < 4; ++j) {
        xw[(krow * 4 + j) * 34 + l16] = a0[j];
        xw[(krow * 4 + j) * 34 + 16 + l16] = a1[j];
      }
      UQ zq;
      #pragma unroll
      for (int q = 0; q < 8; ++q) zq.h[q] = f2b(sigm(xw[r4 * 34 + cb + q]));
      u16* zdst = ZZB + (size_t)(m0 + r4) * 512 + cw + cb;
      cstore64(zdst, zq.u[0]); cstore64(zdst + 4, zq.u[1]);
      asm volatile("s_waitcnt vmcnt(0)" ::: "memory");
      if (lane == 0) cstore32(FB + 32 + pw, (u32)(t + 1));
      __syncthreads();                       // B3 (protect panel)
    }
  } else {
    // ================= gamma producer =================
    bfrag BG[8][2];
    #pragma unroll
    for (int ct = 0; ct < 8; ++ct)
      #pragma unroll
      for (int kx = 0; kx < 2; ++kx)
        BG[ct][kx] = ldfrag(Wdg + (size_t)(wid * 128 + ct * 16 + l16) * 64 + kx * 32 + krow * 8);
    float gb4[4][8];
    #pragma unroll
    for (int grp = 0; grp < 4; ++grp)
      #pragma unroll
      for (int q = 0; q < 8; ++q) gb4[grp][q] = bdg[wid * 128 + grp * 32 + cb + q];

    for (int tt = 1; tt < NS; ++tt) {
      if (wid == 0) {
        const u32* wp = (lane < 16) ? (FB + lane) : FB;
        u32 tgt = (lane < 16 && tt >= 3) ? (u32)(tt - 2) : 0u;
        if (!poll_ge(wp, tgt)) s_ab = 1;
      }
      if (tid < 128) {
        const int kb = tid >> 4, row = tid & 15;
        const u16* sp = DELTA + ((size_t)tt * NB + m0 + row) * 64 + kb * 8;
        *(uint4*)&panel[(kb * 16 + row) * 8] = *(const uint4*)sp;
      }
      __syncthreads();
      if (s_ab) break;
      u16* orow_ = GAMB + (((size_t)(tt & 1) * 16 + rb) * 16 + r4) * 512 + wid * 128;
      #pragma unroll
      for (int grp = 0; grp < 4; ++grp) {
        f32x4 ac0 = Z4, ac1 = Z4;
        #pragma unroll
        for (int kx = 0; kx < 2; ++kx) {
          bfrag a = *(const bfrag*)&panel[((kx * 4 + krow) * 16 + l16) * 8];
          ac0 = MFMA(a, BG[grp*2][kx], ac0); ac1 = MFMA(a, BG[grp*2+1][kx], ac1);
        }
        #pragma unroll
        for (int j = 0; j < 4; ++j) { xw[(krow*4+j)*34 + l16] = ac0[j]; xw[(krow*4+j)*34 + 16 + l16] = ac1[j]; }
        UQ ov;
        #pragma unroll
        for (int q = 0; q < 8; ++q)
          ov.h[q] = f2b(__expf(-fmaxf(0.f, xw[r4 * 34 + cb + q] + gb4[grp][q])));
        cstore64(orow_ + grp * 32 + cb, ov.u[0]); cstore64(orow_ + grp * 32 + cb + 4, ov.u[1]);
      }
      asm volatile("s_waitcnt vmcnt(0)" ::: "memory");
      __syncthreads();
      if (tid == 0) cstore32(FB + 48, (u32)tt);
    }
  }
}

// ---------------- post kernels ----------------

__global__ void attn_k(const u16* __restrict__ HALL, const float* __restrict__ av,
                       float* __restrict__ ATTN){
  const int b = blockIdx.x, tid = threadIdx.x, lane = tid & 63, wid = tid >> 6;
  __shared__ float avs[512], wgt[256], red[8];
  for (int i = tid; i < 512; i += 256) avs[i] = av[i];
  __syncthreads();
  float val = -3.0e38f;
  if (tid < NS) {
    const u16* hp = HALL + ((size_t)tid * NB + b) * 512;
    float acc = 0.f;
    for (int h = 0; h < 512; h += 8) {
      UQ w; w.q = *(const uint4*)(hp + h);
      #pragma unroll
      for (int j = 0; j < 8; ++j) acc += b2f(w.h[j]) * avs[h + j];
    }
    val = acc * 0.04419417382415922f;   // 1/sqrt(512)
  }
  float m = val;
  #pragma unroll
  for (int off = 32; off; off >>= 1) m = fmaxf(m, __shfl_xor(m, off, 64));
  if (lane == 0) red[wid] = m;
  __syncthreads();
  m = fmaxf(fmaxf(red[0], red[1]), fmaxf(red[2], red[3]));
  float e = (tid < NS) ? __expf(val - m) : 0.f;
  float sum = e;
  #pragma unroll
  for (int off = 32; off; off >>= 1) sum += __shfl_xor(sum, off, 64);
  if (lane == 0) red[4 + wid] = sum;
  __syncthreads();
  const float ssum = red[4] + red[5] + red[6] + red[7];
  wgt[tid] = e / ssum;
  __syncthreads();
  float a0 = 0.f, a1 = 0.f;
  const int h0 = tid * 2;
  for (int s = 0; s < NS; ++s) {
    float w = wgt[s];
    u32 pr = *(const u32*)(HALL + ((size_t)s * NB + b) * 512 + h0);
    a0 += w * b2f((u16)(pr & 0xFFFFu));
    a1 += w * b2f((u16)(pr >> 16));
  }
  ATTN[(size_t)b * 512 + h0] = a0;
  ATTN[(size_t)b * 512 + h0 + 1] = a1;
}

__global__ void out_k(const float* __restrict__ ATTN, const float* __restrict__ Ain,
                      const float* __restrict__ WT, const float* __restrict__ bout,
                      float* __restrict__ OUT){
  const int g = blockIdx.x, tid = threadIdx.x;
  __shared__ float ah[4][520];
  for (int i = tid; i < 4 * 520; i += 256) {
    int bb = i / 520, k = i % 520;
    int b = g * 4 + bb;
    ah[bb][k] = (k < 512) ? ATTN[(size_t)b * 512 + k] : Ain[b * 8 + (k - 512)];
  }
  __syncthreads();
  #pragma unroll
  for (int part = 0; part < 2; ++part) {
    const int ho = part * 256 + tid;
    float a0 = bout[ho], a1 = a0, a2 = a0, a3 = a0;
    for (int k = 0; k < 520; ++k) {
      float w = WT[(size_t)k * 512 + ho];
      a0 += ah[0][k] * w; a1 += ah[1][k] * w; a2 += ah[2][k] * w; a3 += ah[3][k] * w;
    }
    OUT[(size_t)(g * 4 + 0) * 512 + ho] = a0;
    OUT[(size_t)(g * 4 + 1) * 512 + ho] = a1;
    OUT[(size_t)(g * 4 + 2) * 512 + ho] = a2;
    OUT[(size_t)(g * 4 + 3) * 512 + ho] = a3;
  }
}

// ---------------- host ----------------

extern "C" void kernel_launch(void* const* d_in, const int* in_sizes, int n_in,
                              void* d_out, int out_size, void* d_ws, size_t ws_size,
                              hipStream_t stream) {
  (void)in_sizes; (void)n_in; (void)out_size; (void)ws_size;
  const float* x    = (const float*)d_in[0];
  const float* a_in = (const float*)d_in[1];
  const float* tc   = (const float*)d_in[2];
  const float* mask = (const float*)d_in[3];
  const float* wdgx = (const float*)d_in[4];
  const float* bdgx = (const float*)d_in[5];
  const float* Wdgh = (const float*)d_in[6];
  const float* bdgh = (const float*)d_in[7];
  const float* Wm   = (const float*)d_in[8];
  const float* Um   = (const float*)d_in[9];
  const float* Vm   = (const float*)d_in[10];
  const float* bvv  = (const float*)d_in[11];
  const float* attv = (const float*)d_in[12];
  const float* Wout = (const float*)d_in[13];
  const float* bout = (const float*)d_in[14];

  char* ws = (char*)d_ws;
  size_t o = 0;
  auto al = [&](size_t sz) { size_t r = o; o += (sz + 255) & ~(size_t)255; return r; };
  u32*   flags = (u32*)  (ws + al(16 * 64 * 4));
  float* XMEAN = (float*)(ws + al(256));
  float* PX    = (float*)(ws + al((size_t)NS * 64 * 4));
  float* PM    = (float*)(ws + al((size_t)NS * 64 * 4));
  u16*   XHAT  = (u16*)  (ws + al((size_t)NS * NB * 64 * 2));
  u16*   MASKB = (u16*)  (ws + al((size_t)NS * NB * 64 * 2));
  u16*   DELTA = (u16*)  (ws + al((size_t)NS * NB * 64 * 2));
  u16*   HDECB = (u16*)  (ws + al((size_t)NB * NH * 2));
  u16*   RHB   = (u16*)  (ws + al((size_t)NB * NH * 2));
  u16*   ZZB   = (u16*)  (ws + al((size_t)NB * NH * 2));
  u16*   GAMB  = (u16*)  (ws + al((size_t)2 * 16 * 16 * 512 * 2));
  u16*   HALL  = (u16*)  (ws + al((size_t)NS * NB * NH * 2));
  float* ATTN  = (float*)(ws + al((size_t)NB * NH * 4));
  float* WT    = (float*)(ws + al((size_t)520 * 512 * 4));

  hipMemsetAsync(flags, 0, 16 * 64 * 4, stream);

  transpose_k<<<(520 * 512 + 255) / 256, 256, 0, stream>>>(Wout, WT);
  mean1_k<<<NS, 256, 0, stream>>>(x, mask, PX, PM);
  mean2_k<<<1, 64, 0, stream>>>(PX, PM, XMEAN);
  prep_k<<<NB * ND / 256, 256, 0, stream>>>(x, mask, tc, wdgx, bdgx, XMEAN, XHAT, MASKB, DELTA);
  grud_rnn<<<144, 256, 0, stream>>>(Um, Wm, Vm, bvv, Wdgh, bdgh, XHAT, MASKB, DELTA,
                                    HDECB, RHB, ZZB, GAMB, HALL, flags);
  attn_k<<<NB, 256, 0, stream>>>(HALL, attv, ATTN);
  out_k<<<64, 256, 0, stream>>>(ATTN, a_in, WT, bout, (float*)d_out);
}